// Round 1
// baseline (272.442 us; speedup 1.0000x reference)
//
#include <hip/hip_runtime.h>
#include <math.h>

// FilterDetection: score threshold + morphological opening (erode 4x4,
// dilate 4x4) on 32x1024x1024 f32.
//
// Round-9 design (= round-8 structure + two safe changes):
//   (a) XCD-aware block swizzle: 1024 mask blocks are chunked 128-per-XCD so
//       adjacent strips (sharing 6 halo rows) run on the same XCD -> halo
//       re-reads hit that XCD's L2 instead of HBM. Bijective since
//       MASK_BLOCKS % 8 == 0.
//   (b) Two-level sliding pipelines for the vertical 4-row min/max
//       (q_t = min(hm_t, hm_{t-1}); e = min(q_t, q_{t-2}), same for max):
//       2 ops/col instead of 3, and the cm[11] column-pad array (+22 ops/row)
//       is replaced by 3 per-lane-constant selects on ec[0]/ec[9]/ec[10].
//       Bit-identical semantics (pure min/max algebra, no NaNs in domain);
//       frees ~11 VGPRs for deeper compiler load lookahead.
//
// Round-8 structure kept verbatim: 8 columns per lane, one wave = one full
// 512-col segment of a 16-row strip; per row 4 dword-aligned vector loads
// covering raw cols c0-3..c0+10; no LDS, no barriers, no cross-lane ops;
// image-edge lanes handled by address clamp + per-lane-constant selects.
//
// Threshold deferred to store (monotone th() commutes with min/max; verified
// absmax=0 rounds 1-7). Store guard keeps writes strictly inside the strip
// (round-6 race bug). Plain coherent stores only (round-5 nt-store hazard).
//
// Window geometry (from lax.reduce_window padding):
//   erode : offsets [-2..+1] both axes, OOB = +inf
//   dilate: offsets [-1..+2] both axes, OOB = -inf
// Output col j needs raw cols j-3..j+3; eroded values at OOB cols/rows are
// -inf (dilation pad), raw OOB values are +inf (erosion pad).

#define H 1024
#define W 1024
#define R 16
#define STRIPS (H / R)                    // 64
#define SEGS 2                            // 512-col segments per row
#define BATCH 32
#define TASKS (STRIPS * SEGS * BATCH)     // 4096 wave-tasks
#define MASK_BLOCKS (TASKS / 4)           // 1024 blocks, 4 waves each
#define N_SCORE 32000
#define SCORE_BLOCKS ((N_SCORE + 255) / 256)

__device__ __forceinline__ float th(float v) { return v >= 0.5f ? v : 0.0f; }

__global__ __launch_bounds__(256, 4)
void fused_kernel(const float* __restrict__ score,
                  const float* __restrict__ mask,
                  float* __restrict__ out) {
    const int bid0 = blockIdx.x;
    const int tid  = threadIdx.x;

    if (bid0 >= MASK_BLOCKS) {              // tail blocks: score threshold
        int i = (bid0 - MASK_BLOCKS) * 256 + tid;
        if (i < N_SCORE) out[i] = th(score[i]);
        return;
    }

    // XCD swizzle: contiguous chunk of 128 blocks (= contiguous strips of 4
    // images) per XCD for halo-row L2 reuse. Bijective permutation of
    // [0,1024): bid = (bid0 % 8) * 128 + bid0 / 8.
    const int bid = (bid0 & 7) * (MASK_BLOCKS / 8) + (bid0 >> 3);

    const int wave = tid >> 6;
    const int lane = tid & 63;
    const int task = bid * 4 + wave;        // one wave = one (img,strip,seg)
    const int b    = task >> 7;             // 128 tasks per image
    const int rem  = task & 127;
    const int strip= rem >> 1;
    const int seg  = rem & 1;
    const int y0   = strip * R;
    const int c0   = seg * 512 + lane * 8;  // first of this lane's 8 columns

    const float* img  = mask + (size_t)b * (H * W);
    float*       outp = out + N_SCORE + (size_t)b * (H * W);

    const bool eL = (c0 == 0);              // needs cols < 0 (pad)
    const bool eR = (c0 == W - 8);          // needs cols >= W (pad)
    // Clamped load offsets (floats), all guaranteed in [0, W-4]/[0, W-2]:
    const int o0 = eL ? 0       : (c0 - 3); // raw cols c0-3..c0   (4)
    const int o1 = c0 + 1;                  // raw cols c0+1..c0+4 (4)
    const int o2 = eR ? (W - 4) : (c0 + 5); // raw cols c0+5..c0+8 (4)
    const int o3 = eR ? (W - 2) : (c0 + 9); // raw cols c0+9..c0+10 (2)

    // Vertical-min pipeline state over hmin rows (window t-3..t):
    //   hmP = hm_{t-1}; q1 = min(hm_{t-1},hm_{t-2}); q2 = min(hm_{t-2},hm_{t-3})
    float hmP[11], q1[11], q2[11];
    #pragma unroll
    for (int m = 0; m < 11; ++m) { hmP[m] = q1[m] = q2[m] = INFINITY; }
    // Vertical-max pipeline state over hmax rows (window r-3..r):
    //   hxP = hx_{r-1}; u1 = max(hx_{r-1},hx_{r-2}); u2 = max(hx_{r-2},hx_{r-3})
    float hxP[8], u1[8], u2[8];
    #pragma unroll
    for (int j = 0; j < 8; ++j)  { hxP[j] = u1[j] = u2[j] = -INFINITY; }

    #pragma unroll
    for (int it = 0; it < R + 6; ++it) {
        const int t = y0 - 3 + it;          // raw row consumed this iteration

        // ---- load raw cols c0-3..c0+10 into ar[0..13] (OOB -> +inf) ----
        float ar[14];
        if (t >= 0 && t < H) {
            const float* row = img + (size_t)t * W;
            float4 L0, L1, L2; float2 L3;
            __builtin_memcpy(&L0, row + o0, 16);   // dword-aligned dwordx4
            __builtin_memcpy(&L1, row + o1, 16);
            __builtin_memcpy(&L2, row + o2, 16);
            __builtin_memcpy(&L3, row + o3, 8);
            ar[0]  = eL ? INFINITY : L0.x;   // col c0-3
            ar[1]  = eL ? INFINITY : L0.y;   // col c0-2
            ar[2]  = eL ? INFINITY : L0.z;   // col c0-1
            ar[3]  = eL ? L0.x     : L0.w;   // col c0
            ar[4]  = L1.x;  ar[5] = L1.y;  ar[6] = L1.z;  ar[7] = L1.w;
            ar[8]  = eR ? L2.y : L2.x;       // col c0+5
            ar[9]  = eR ? L2.z : L2.y;       // col c0+6
            ar[10] = eR ? L2.w : L2.z;       // col c0+7
            ar[11] = eR ? INFINITY : L2.w;   // col c0+8
            ar[12] = eR ? INFINITY : L3.x;   // col c0+9
            ar[13] = eR ? INFINITY : L3.y;   // col c0+10
        } else {
            #pragma unroll
            for (int k = 0; k < 14; ++k) ar[k] = INFINITY;
        }

        // ---- hmin row t via shared pairwise mins ----
        // hm[m] = min(ar[m..m+3]) for eroded col c0-1+m
        float p[13];
        #pragma unroll
        for (int m = 0; m < 13; ++m) p[m] = fminf(ar[m], ar[m + 1]);
        float hm[11];
        #pragma unroll
        for (int m = 0; m < 11; ++m) hm[m] = fminf(p[m], p[m + 2]);

        // ---- eroded row r = t-1: min over hm rows t-3..t = min(qt, q2) ----
        const int r = t - 1;
        const float rlim = (r >= 0 && r < H) ? INFINITY : -INFINITY;  // uniform
        float qt[11], ec[11];
        #pragma unroll
        for (int m = 0; m < 11; ++m) {
            qt[m] = fminf(hmP[m], hm[m]);
            ec[m] = fminf(fminf(qt[m], q2[m]), rlim);
        }
        // Column pad (-inf) only exists for image-edge lanes:
        //   eL: eroded col c0-1 = -1; eR: eroded cols c0+8+{1,2} = 1024,1025.
        ec[0]  = eL ? -INFINITY : ec[0];
        ec[9]  = eR ? -INFINITY : ec[9];
        ec[10] = eR ? -INFINITY : ec[10];

        // shift min pipeline (renamed under full unroll)
        #pragma unroll
        for (int m = 0; m < 11; ++m) { q2[m] = q1[m]; q1[m] = qt[m]; hmP[m] = hm[m]; }

        // ---- hmax row r via shared pairwise maxes; start vertical max ----
        float p2[10];
        #pragma unroll
        for (int j = 0; j < 10; ++j) p2[j] = fmaxf(ec[j], ec[j + 1]);
        float hx[8], ur[8];
        #pragma unroll
        for (int j = 0; j < 8; ++j) {
            hx[j] = fmaxf(p2[j], p2[j + 2]);       // hmax col c0+j, row r
            ur[j] = fmaxf(hxP[j], hx[j]);          // max(hx_r, hx_{r-1})
        }

        // ---- output row y = t-3: max over hx rows y-1..y+2 = max(ur, u2) ----
        if (it >= 6) {                       // strictly inside the strip
            const int y = t - 3;
            float o[8];
            #pragma unroll
            for (int j = 0; j < 8; ++j)
                o[j] = th(fmaxf(ur[j], u2[j]));
            float* po = outp + (size_t)y * W + c0;
            float4 s0 = make_float4(o[0], o[1], o[2], o[3]);
            float4 s1 = make_float4(o[4], o[5], o[6], o[7]);
            *(float4*)(po)     = s0;
            *(float4*)(po + 4) = s1;
        }

        // shift max pipeline
        #pragma unroll
        for (int j = 0; j < 8; ++j) { u2[j] = u1[j]; u1[j] = ur[j]; hxP[j] = hx[j]; }
    }
}

extern "C" void kernel_launch(void* const* d_in, const int* in_sizes, int n_in,
                              void* d_out, int out_size, void* d_ws, size_t ws_size,
                              hipStream_t stream) {
    const float* score = (const float*)d_in[0];
    const float* mask  = (const float*)d_in[1];
    float* out = (float*)d_out;

    const int grid = MASK_BLOCKS + SCORE_BLOCKS;
    fused_kernel<<<grid, 256, 0, stream>>>(score, mask, out);
}

// Round 2
// 265.223 us; speedup vs baseline: 1.0272x; 1.0272x over previous
//
#include <hip/hip_runtime.h>
#include <math.h>

// FilterDetection: score threshold + morphological opening (erode 4x4,
// dilate 4x4) on 32x1024x1024 f32.
//
// Round-10 design (= round-9 + explicit 2-deep row prefetch):
//   Round-1-counter theory: VGPR dropped to 64 (state alone = 57 floats), so
//   the compiler had zero headroom to keep the next row's loads in flight ->
//   every iteration serialized on load-use latency (VALUBusy 14%, HBM 39% of
//   achievable, 86% stall). Fix: double-buffered unconditional row loads
//   (address-clamped), issue row t+2 right after row t is folded into hm[].
//   28 extra load regs + addresses -> ~100-120 VGPR, still 4 waves/SIMD under
//   __launch_bounds__(256,4). OOB rows folded to +inf AFTER the horizontal
//   min (11 uniform selects) instead of branching around the loads.
//
// Kept from rounds 8-9: 8 cols/lane, one wave = one 512-col segment of a
// 16-row strip; 4 dword-aligned vector loads/row; no LDS/barriers/cross-lane;
// XCD-chunked block swizzle (bijective, MASK_BLOCKS%8==0) for halo L2 reuse;
// two-level sliding min/max pipelines (2 ops/col vertical); edge lanes via
// address clamp + per-lane-constant selects; threshold deferred to store
// (monotone, verified absmax=0 through round 9); store guard strictly inside
// strip; plain coherent stores.
//
// Window geometry (from lax.reduce_window padding):
//   erode : offsets [-2..+1] both axes, OOB = +inf
//   dilate: offsets [-1..+2] both axes, OOB = -inf

#define H 1024
#define W 1024
#define R 16
#define STRIPS (H / R)                    // 64
#define SEGS 2                            // 512-col segments per row
#define BATCH 32
#define TASKS (STRIPS * SEGS * BATCH)     // 4096 wave-tasks
#define MASK_BLOCKS (TASKS / 4)           // 1024 blocks, 4 waves each
#define N_SCORE 32000
#define SCORE_BLOCKS ((N_SCORE + 255) / 256)
#define ITERS (R + 6)                     // 22 row-iterations per wave

__device__ __forceinline__ float th(float v) { return v >= 0.5f ? v : 0.0f; }

__global__ __launch_bounds__(256, 4)
void fused_kernel(const float* __restrict__ score,
                  const float* __restrict__ mask,
                  float* __restrict__ out) {
    const int bid0 = blockIdx.x;
    const int tid  = threadIdx.x;

    if (bid0 >= MASK_BLOCKS) {              // tail blocks: score threshold
        int i = (bid0 - MASK_BLOCKS) * 256 + tid;
        if (i < N_SCORE) out[i] = th(score[i]);
        return;
    }

    // XCD swizzle: contiguous chunk of 128 blocks per XCD for halo L2 reuse.
    const int bid = (bid0 & 7) * (MASK_BLOCKS / 8) + (bid0 >> 3);

    const int wave = tid >> 6;
    const int lane = tid & 63;
    const int task = bid * 4 + wave;        // one wave = one (img,strip,seg)
    const int b    = task >> 7;             // 128 tasks per image
    const int rem  = task & 127;
    const int strip= rem >> 1;
    const int seg  = rem & 1;
    const int y0   = strip * R;
    const int c0   = seg * 512 + lane * 8;  // first of this lane's 8 columns

    const float* img  = mask + (size_t)b * (H * W);
    float*       outp = out + N_SCORE + (size_t)b * (H * W);

    const bool eL = (c0 == 0);              // needs cols < 0 (pad)
    const bool eR = (c0 == W - 8);          // needs cols >= W (pad)
    // Clamped load offsets (floats), all guaranteed in [0, W-4]/[0, W-2]:
    const int o0 = eL ? 0       : (c0 - 3); // raw cols c0-3..c0   (4)
    const int o1 = c0 + 1;                  // raw cols c0+1..c0+4 (4)
    const int o2 = eR ? (W - 4) : (c0 + 5); // raw cols c0+5..c0+8 (4)
    const int o3 = eR ? (W - 2) : (c0 + 9); // raw cols c0+9..c0+10 (2)

    // Double-buffered raw row loads (prefetch depth 2). All indices into
    // these arrays are compile-time constants under the full unroll, so they
    // live in VGPRs (rule: no runtime-indexed ext_vector arrays).
    float4 B0[2], B1[2], B2[2]; float2 B3[2];

    // Issue the 4 unconditional (address-clamped) loads for iteration IT2.
#define ISSUE(IT2) do {                                                  \
        int t_  = y0 - 3 + (IT2);                                        \
        int tc_ = t_ < 0 ? 0 : (t_ >= H ? H - 1 : t_);   /* uniform */   \
        const float* row_ = img + (size_t)tc_ * W;                       \
        __builtin_memcpy(&B0[(IT2) & 1], row_ + o0, 16);                 \
        __builtin_memcpy(&B1[(IT2) & 1], row_ + o1, 16);                 \
        __builtin_memcpy(&B2[(IT2) & 1], row_ + o2, 16);                 \
        __builtin_memcpy(&B3[(IT2) & 1], row_ + o3, 8);                  \
    } while (0)

    ISSUE(0);
    ISSUE(1);

    // Vertical-min pipeline state over hmin rows (window t-3..t):
    //   hmP = hm_{t-1}; q1 = min(hm_{t-1},hm_{t-2}); q2 = min(hm_{t-2},hm_{t-3})
    float hmP[11], q1[11], q2[11];
    #pragma unroll
    for (int m = 0; m < 11; ++m) { hmP[m] = q1[m] = q2[m] = INFINITY; }
    // Vertical-max pipeline state over hmax rows (window r-3..r):
    float hxP[8], u1[8], u2[8];
    #pragma unroll
    for (int j = 0; j < 8; ++j)  { hxP[j] = u1[j] = u2[j] = -INFINITY; }

    #pragma unroll
    for (int it = 0; it < ITERS; ++it) {
        const int t   = y0 - 3 + it;        // raw row consumed this iteration
        const int buf = it & 1;
        const bool rowOK = (t >= 0) && (t < H);            // wave-uniform

        // ---- consume buffered row: raw cols c0-3..c0+10 -> ar[0..13] ----
        float4 L0 = B0[buf], L1 = B1[buf], L2 = B2[buf]; float2 L3 = B3[buf];
        float ar[14];
        ar[0]  = eL ? INFINITY : L0.x;   // col c0-3
        ar[1]  = eL ? INFINITY : L0.y;   // col c0-2
        ar[2]  = eL ? INFINITY : L0.z;   // col c0-1
        ar[3]  = eL ? L0.x     : L0.w;   // col c0
        ar[4]  = L1.x;  ar[5] = L1.y;  ar[6] = L1.z;  ar[7] = L1.w;
        ar[8]  = eR ? L2.y : L2.x;       // col c0+5
        ar[9]  = eR ? L2.z : L2.y;       // col c0+6
        ar[10] = eR ? L2.w : L2.z;       // col c0+7
        ar[11] = eR ? INFINITY : L2.w;   // col c0+8
        ar[12] = eR ? INFINITY : L3.x;   // col c0+9
        ar[13] = eR ? INFINITY : L3.y;   // col c0+10

        // ---- hmin row t via shared pairwise mins; fold OOB row to +inf ----
        float p[13];
        #pragma unroll
        for (int m = 0; m < 13; ++m) p[m] = fminf(ar[m], ar[m + 1]);
        float hm[11];
        #pragma unroll
        for (int m = 0; m < 11; ++m) {
            float v = fminf(p[m], p[m + 2]);
            hm[m] = rowOK ? v : INFINITY;    // erosion pad for OOB raw rows
        }

        // ---- prefetch row for iteration it+2 into the buffer just freed ----
        if (it + 2 < ITERS) ISSUE(it + 2);

        // ---- eroded row r = t-1: min over hm rows t-3..t = min(qt, q2) ----
        const int r = t - 1;
        const float rlim = (r >= 0 && r < H) ? INFINITY : -INFINITY;  // uniform
        float qt[11], ec[11];
        #pragma unroll
        for (int m = 0; m < 11; ++m) {
            qt[m] = fminf(hmP[m], hm[m]);
            ec[m] = fminf(fminf(qt[m], q2[m]), rlim);
        }
        // Column pad (-inf) only exists for image-edge lanes:
        ec[0]  = eL ? -INFINITY : ec[0];
        ec[9]  = eR ? -INFINITY : ec[9];
        ec[10] = eR ? -INFINITY : ec[10];

        // shift min pipeline (renamed under full unroll)
        #pragma unroll
        for (int m = 0; m < 11; ++m) { q2[m] = q1[m]; q1[m] = qt[m]; hmP[m] = hm[m]; }

        // ---- hmax row r via shared pairwise maxes; start vertical max ----
        float p2[10];
        #pragma unroll
        for (int j = 0; j < 10; ++j) p2[j] = fmaxf(ec[j], ec[j + 1]);
        float hx[8], ur[8];
        #pragma unroll
        for (int j = 0; j < 8; ++j) {
            hx[j] = fmaxf(p2[j], p2[j + 2]);       // hmax col c0+j, row r
            ur[j] = fmaxf(hxP[j], hx[j]);          // max(hx_r, hx_{r-1})
        }

        // ---- output row y = t-3: max over hx rows y-1..y+2 = max(ur, u2) ----
        if (it >= 6) {                       // strictly inside the strip
            const int y = t - 3;
            float o[8];
            #pragma unroll
            for (int j = 0; j < 8; ++j)
                o[j] = th(fmaxf(ur[j], u2[j]));
            float* po = outp + (size_t)y * W + c0;
            float4 s0 = make_float4(o[0], o[1], o[2], o[3]);
            float4 s1 = make_float4(o[4], o[5], o[6], o[7]);
            *(float4*)(po)     = s0;
            *(float4*)(po + 4) = s1;
        }

        // shift max pipeline
        #pragma unroll
        for (int j = 0; j < 8; ++j) { u2[j] = u1[j]; u1[j] = ur[j]; hxP[j] = hx[j]; }
    }
#undef ISSUE
}

extern "C" void kernel_launch(void* const* d_in, const int* in_sizes, int n_in,
                              void* d_out, int out_size, void* d_ws, size_t ws_size,
                              hipStream_t stream) {
    const float* score = (const float*)d_in[0];
    const float* mask  = (const float*)d_in[1];
    float* out = (float*)d_out;

    const int grid = MASK_BLOCKS + SCORE_BLOCKS;
    fused_kernel<<<grid, 256, 0, stream>>>(score, mask, out);
}

// Round 3
// 263.459 us; speedup vs baseline: 1.0341x; 1.0067x over previous
//
#include <hip/hip_runtime.h>
#include <math.h>

// FilterDetection: score threshold + morphological opening (erode 4x4,
// dilate 4x4) on 32x1024x1024 f32.
//
// Round-11 design: 4 cols/lane, 256-col segments, 8192 wave-tasks.
//   Round-2-counter theory: compiler pins VGPR=64 (wants 8 waves/EU) and
//   serializes any state that doesn't fit -> per-wave ILP is capped. But the
//   grid (1024 mask blocks) only supplied 4 blocks/CU -> occupancy 37%,
//   latency-bound at 2.85 TB/s. Fix: halve the per-wave task (4 cols/lane)
//   so state (33 floats) + 2-deep prefetch (20 floats) genuinely fits 64
//   VGPR, and double the grid to 2048 mask blocks = 8 blocks/CU = 32
//   waves/CU. TLP does the latency hiding the register file couldn't.
//   Block = 4 waves = 4 segments of the SAME strip (same 22 rows) -> L1/L2
//   row locality within a block.
//
// Kept: dword-aligned unaligned vector loads; no LDS/barriers/cross-lane;
// XCD-chunked bijective block swizzle (2048 % 8 == 0); two-level sliding
// min/max pipelines; edge lanes via address clamp + per-lane-constant
// selects; threshold deferred to store (monotone; absmax=0 rounds 1-10);
// stores strictly inside strip; plain coherent stores.
//
// Window geometry (from lax.reduce_window padding):
//   erode : offsets [-2..+1] both axes, OOB = +inf
//   dilate: offsets [-1..+2] both axes, OOB = -inf
// Output col j needs raw cols j-3..j+3. Per lane (4 out cols c0..c0+3):
// raw c0-3..c0+6 (10), eroded c0-1..c0+5 (7).

#define H 1024
#define W 1024
#define R 16
#define STRIPS (H / R)                    // 64
#define SEGS 4                            // 256-col segments per row
#define BATCH 32
#define TASKS (STRIPS * SEGS * BATCH)     // 8192 wave-tasks
#define MASK_BLOCKS (TASKS / 4)           // 2048 blocks, 4 waves each
#define N_SCORE 32000
#define SCORE_BLOCKS ((N_SCORE + 255) / 256)
#define ITERS (R + 6)                     // 22 row-iterations per wave

__device__ __forceinline__ float th(float v) { return v >= 0.5f ? v : 0.0f; }

__global__ __launch_bounds__(256, 4)
void fused_kernel(const float* __restrict__ score,
                  const float* __restrict__ mask,
                  float* __restrict__ out) {
    const int bid0 = blockIdx.x;
    const int tid  = threadIdx.x;

    if (bid0 >= MASK_BLOCKS) {              // tail blocks: score threshold
        int i = (bid0 - MASK_BLOCKS) * 256 + tid;
        if (i < N_SCORE) out[i] = th(score[i]);
        return;
    }

    // XCD swizzle: contiguous chunk of 256 blocks per XCD for halo L2 reuse.
    const int bid = (bid0 & 7) * (MASK_BLOCKS / 8) + (bid0 >> 3);

    const int wave = tid >> 6;
    const int lane = tid & 63;
    const int task = bid * 4 + wave;        // one wave = one (img,strip,seg)
    const int b    = task >> 8;             // 256 tasks per image
    const int rem  = task & 255;
    const int strip= rem >> 2;              // 4 waves of a block share strip
    const int seg  = rem & 3;
    const int y0   = strip * R;
    const int c0   = seg * 256 + lane * 4;  // first of this lane's 4 columns

    const float* img  = mask + (size_t)b * (H * W);
    float*       outp = out + N_SCORE + (size_t)b * (H * W);

    const bool eL = (c0 == 0);              // needs cols < 0 (pad)
    const bool eR = (c0 == W - 4);          // needs cols >= W (pad)
    // Clamped load offsets (floats), all in-bounds:
    const int o0 = eL ? 0       : (c0 - 3); // raw cols c0-3..c0   (4)
    const int o1 = eR ? (W - 4) : (c0 + 1); // raw cols c0+1..c0+4 (4)
    const int o2 = eR ? (W - 2) : (c0 + 5); // raw cols c0+5..c0+6 (2)

    // Double-buffered raw row loads (prefetch depth 2); all indices
    // compile-time under full unroll -> stays in VGPRs.
    float4 B0[2], B1[2]; float2 B2[2];

#define ISSUE(IT2) do {                                                  \
        int t_  = y0 - 3 + (IT2);                                        \
        int tc_ = t_ < 0 ? 0 : (t_ >= H ? H - 1 : t_);   /* uniform */   \
        const float* row_ = img + (size_t)tc_ * W;                       \
        __builtin_memcpy(&B0[(IT2) & 1], row_ + o0, 16);                 \
        __builtin_memcpy(&B1[(IT2) & 1], row_ + o1, 16);                 \
        __builtin_memcpy(&B2[(IT2) & 1], row_ + o2, 8);                  \
    } while (0)

    ISSUE(0);
    ISSUE(1);

    // Vertical-min pipeline over hmin rows (window t-3..t), 7 eroded cols:
    //   hmP = hm_{t-1}; q1 = min(hm_{t-1},hm_{t-2}); q2 = min(hm_{t-2},hm_{t-3})
    float hmP[7], q1[7], q2[7];
    #pragma unroll
    for (int m = 0; m < 7; ++m) { hmP[m] = q1[m] = q2[m] = INFINITY; }
    // Vertical-max pipeline over hmax rows (window r-3..r), 4 out cols:
    float hxP[4], u1[4], u2[4];
    #pragma unroll
    for (int j = 0; j < 4; ++j)  { hxP[j] = u1[j] = u2[j] = -INFINITY; }

    #pragma unroll
    for (int it = 0; it < ITERS; ++it) {
        const int t   = y0 - 3 + it;        // raw row consumed this iteration
        const int buf = it & 1;
        const bool rowOK = (t >= 0) && (t < H);            // wave-uniform

        // ---- consume buffered row: raw cols c0-3..c0+6 -> ar[0..9] ----
        float4 L0 = B0[buf], L1 = B1[buf]; float2 L2 = B2[buf];
        float ar[10];
        ar[0] = eL ? INFINITY : L0.x;    // col c0-3
        ar[1] = eL ? INFINITY : L0.y;    // col c0-2
        ar[2] = eL ? INFINITY : L0.z;    // col c0-1
        ar[3] = eL ? L0.x     : L0.w;    // col c0
        ar[4] = eR ? L1.y     : L1.x;    // col c0+1
        ar[5] = eR ? L1.z     : L1.y;    // col c0+2
        ar[6] = eR ? L1.w     : L1.z;    // col c0+3
        ar[7] = eR ? INFINITY : L1.w;    // col c0+4
        ar[8] = eR ? INFINITY : L2.x;    // col c0+5
        ar[9] = eR ? INFINITY : L2.y;    // col c0+6

        // ---- hmin row t via shared pairwise mins; fold OOB row to +inf ----
        float p[9];
        #pragma unroll
        for (int m = 0; m < 9; ++m) p[m] = fminf(ar[m], ar[m + 1]);
        float hm[7];
        #pragma unroll
        for (int m = 0; m < 7; ++m) {
            float v = fminf(p[m], p[m + 2]);
            hm[m] = rowOK ? v : INFINITY;    // erosion pad for OOB raw rows
        }

        // ---- prefetch row for iteration it+2 into the freed buffer ----
        if (it + 2 < ITERS) ISSUE(it + 2);

        // ---- eroded row r = t-1: min over hm rows t-3..t = min(qt, q2) ----
        const int r = t - 1;
        const float rlim = (r >= 0 && r < H) ? INFINITY : -INFINITY;  // uniform
        float qt[7], ec[7];
        #pragma unroll
        for (int m = 0; m < 7; ++m) {
            qt[m] = fminf(hmP[m], hm[m]);
            ec[m] = fminf(fminf(qt[m], q2[m]), rlim);
        }
        // Column pad (-inf), image-edge lanes only:
        //   eL: eroded col c0-1 = -1; eR: eroded cols c0+4,c0+5 = 1024,1025.
        ec[0] = eL ? -INFINITY : ec[0];
        ec[5] = eR ? -INFINITY : ec[5];
        ec[6] = eR ? -INFINITY : ec[6];

        // shift min pipeline (renamed under full unroll)
        #pragma unroll
        for (int m = 0; m < 7; ++m) { q2[m] = q1[m]; q1[m] = qt[m]; hmP[m] = hm[m]; }

        // ---- hmax row r via shared pairwise maxes; start vertical max ----
        float p2[6];
        #pragma unroll
        for (int j = 0; j < 6; ++j) p2[j] = fmaxf(ec[j], ec[j + 1]);
        float hx[4], ur[4];
        #pragma unroll
        for (int j = 0; j < 4; ++j) {
            hx[j] = fmaxf(p2[j], p2[j + 2]);       // hmax col c0+j, row r
            ur[j] = fmaxf(hxP[j], hx[j]);          // max(hx_r, hx_{r-1})
        }

        // ---- output row y = t-3: max over hx rows y-1..y+2 = max(ur, u2) ----
        if (it >= 6) {                       // strictly inside the strip
            const int y = t - 3;
            float o[4];
            #pragma unroll
            for (int j = 0; j < 4; ++j)
                o[j] = th(fmaxf(ur[j], u2[j]));
            float* po = outp + (size_t)y * W + c0;
            *(float4*)(po) = make_float4(o[0], o[1], o[2], o[3]);
        }

        // shift max pipeline
        #pragma unroll
        for (int j = 0; j < 4; ++j) { u2[j] = u1[j]; u1[j] = ur[j]; hxP[j] = hx[j]; }
    }
#undef ISSUE
}

extern "C" void kernel_launch(void* const* d_in, const int* in_sizes, int n_in,
                              void* d_out, int out_size, void* d_ws, size_t ws_size,
                              hipStream_t stream) {
    const float* score = (const float*)d_in[0];
    const float* mask  = (const float*)d_in[1];
    float* out = (float*)d_out;

    const int grid = MASK_BLOCKS + SCORE_BLOCKS;
    fused_kernel<<<grid, 256, 0, stream>>>(score, mask, out);
}